// Round 2
// baseline (23508.330 us; speedup 1.0000x reference)
//
#include <hip/hip_runtime.h>

#define BLOCK 256

// sigmoid(x) = 1/(1+e^-x); fast native exp + fast divide (rel err ~1e-6, fine vs 9e-3 tol)
__device__ __forceinline__ float sigm(float x) {
    return __fdividef(1.0f, 1.0f + __expf(-x));
}
// tanh(x) = 1 - 2/(e^{2x}+1); saturates correctly at +/-inf via inf/0 of __expf
__device__ __forceinline__ float tanhfast(float x) {
    return 1.0f - 2.0f * __fdividef(1.0f, 1.0f + __expf(2.0f * x));
}

// One 8-step LSTM (input dim 1, H=64), PyTorch gate order i,f,g,o.
// h_old lives in LDS at hl[k*BLOCK + tid] (lane-consecutive -> 2 lanes/bank, free).
// c[] and hn[] are register arrays (all indexing constant after unroll).
// xp[t] read from global each step (L1-resident) -- avoids a dynamically-indexed
// register array, which lowers to scratch.
__device__ __forceinline__ void lstm_seq(
    const float* __restrict__ xp,
    const float* __restrict__ Wih, const float* __restrict__ Whh,
    const float* __restrict__ bih, const float* __restrict__ bhh,
    float* __restrict__ hl, int tid,
    float* __restrict__ c, float* __restrict__ hn)
{
    // ---- t = 0 peeled: h = 0, c = 0 -> gates = x*Wih + b only (skips the 64x256 matvec)
    {
        const float xt = xp[0];
        #pragma unroll
        for (int j = 0; j < 64; ++j) {
            float ai = xt * Wih[j]       + bih[j]       + bhh[j];
            float ag = xt * Wih[128 + j] + bih[128 + j] + bhh[128 + j];
            float ao = xt * Wih[192 + j] + bih[192 + j] + bhh[192 + j];
            float cn = sigm(ai) * tanhfast(ag);   // f*0 + i*g
            c[j] = cn;
            float hv = sigm(ao) * tanhfast(cn);
            hn[j] = hv;
            hl[j * BLOCK + tid] = hv;
        }
    }

    #pragma unroll 1
    for (int t = 1; t < 8; ++t) {
        const float xt = xp[t];
        // j in groups of 4: 16 accumulators -> 16 FMAs per LDS read of h[k]
        #pragma unroll
        for (int jg = 0; jg < 16; ++jg) {
            float acc[4][4];
            #pragma unroll
            for (int g = 0; g < 4; ++g)
                #pragma unroll
                for (int u = 0; u < 4; ++u) {
                    int row = g * 64 + jg * 4 + u;
                    acc[g][u] = xt * Wih[row] + bih[row] + bhh[row];
                }
            #pragma unroll 4
            for (int k = 0; k < 64; ++k) {
                float hk = hl[k * BLOCK + tid];
                #pragma unroll
                for (int g = 0; g < 4; ++g)
                    #pragma unroll
                    for (int u = 0; u < 4; ++u)
                        acc[g][u] += hk * Whh[(g * 64 + jg * 4 + u) * 64 + k];  // wave-uniform -> s_load
            }
            #pragma unroll
            for (int u = 0; u < 4; ++u) {
                int j = jg * 4 + u;
                float cn = sigm(acc[1][u]) * c[j] + sigm(acc[0][u]) * tanhfast(acc[2][u]);
                c[j] = cn;
                hn[j] = sigm(acc[3][u]) * tanhfast(cn);
            }
        }
        // commit h_new -> LDS for next step (each thread owns its column: no barrier needed)
        if (t < 7) {
            #pragma unroll
            for (int j = 0; j < 64; ++j) hl[j * BLOCK + tid] = hn[j];
        }
    }
}

// __launch_bounds__(256, 1): min 1 wave/EU -> VGPR budget up to 512. R1 evidence:
// with budget 256 the allocator clamped to 128 VGPRs and spilled c[]/hn[] ->
// 11 GB of scratch HBM traffic. Occupancy is LDS-bound (64 KB -> 2 blocks/CU)
// either way, so a ~180-VGPR allocation costs nothing.
extern "C" __global__ void __launch_bounds__(BLOCK, 1) lstm_fused(
    const float* __restrict__ inputs,
    const float* __restrict__ Wih1, const float* __restrict__ Whh1,
    const float* __restrict__ bih1, const float* __restrict__ bhh1,
    const float* __restrict__ Wih2, const float* __restrict__ Whh2,
    const float* __restrict__ bih2, const float* __restrict__ bhh2,
    const float* __restrict__ mW0, const float* __restrict__ mb0,
    const float* __restrict__ mW1, const float* __restrict__ mb1,
    const float* __restrict__ mW2, const float* __restrict__ mb2,
    const float* __restrict__ pW, const float* __restrict__ pb,
    float* __restrict__ out, int n)
{
    __shared__ float hl[64 * BLOCK];   // 64 KB -> 2 blocks/CU, 8 waves/CU
    const int tid = threadIdx.x;
    const int b = blockIdx.x * BLOCK + tid;
    if (b >= n) return;
    const float* xin = inputs + (size_t)b * 18;

    float out0 = pb[0], out1 = pb[1];

    // ---- MLP branch on feat = x[16:18]; folds hid2 directly into out via pW[:,256:288]
    {
        float f0 = xin[16], f1 = xin[17];
        float hid0[64];
        #pragma unroll
        for (int i = 0; i < 64; ++i) {
            float v = mW0[2 * i] * f0 + mW0[2 * i + 1] * f1 + mb0[i];
            hid0[i] = fmaxf(v, 0.0f);
        }
        #pragma unroll 1
        for (int i = 0; i < 64; ++i) {         // hid1 -> LDS (reused later by LSTM h)
            float a = mb1[i];
            #pragma unroll
            for (int k = 0; k < 64; ++k) a += mW1[i * 64 + k] * hid0[k];
            hl[i * BLOCK + tid] = fmaxf(a, 0.0f);
        }
        #pragma unroll 1
        for (int i = 0; i < 32; ++i) {
            float a = mb2[i];
            #pragma unroll 8
            for (int k = 0; k < 64; ++k) a += mW2[i * 64 + k] * hl[k * BLOCK + tid];
            out0 += pW[256 + i] * a;
            out1 += pW[288 + 256 + i] * a;
        }
    }

    float c[64], hn[64];

    // ---- LSTM1 on x[0:8]; z columns: h1 -> 0..63, c1 -> 64..127
    lstm_seq(xin, Wih1, Whh1, bih1, bhh1, hl, tid, c, hn);
    #pragma unroll
    for (int j = 0; j < 64; ++j) {
        out0 += pW[j] * hn[j]        + pW[64 + j] * c[j];
        out1 += pW[288 + j] * hn[j]  + pW[288 + 64 + j] * c[j];
    }

    // ---- LSTM2 on x[8:16]; z columns: h2 -> 128..191, c2 -> 192..255
    lstm_seq(xin + 8, Wih2, Whh2, bih2, bhh2, hl, tid, c, hn);
    #pragma unroll
    for (int j = 0; j < 64; ++j) {
        out0 += pW[128 + j] * hn[j]       + pW[192 + j] * c[j];
        out1 += pW[288 + 128 + j] * hn[j] + pW[288 + 192 + j] * c[j];
    }

    ((float2*)out)[b] = make_float2(out0, out1);   // 8 B/lane coalesced
}

extern "C" void kernel_launch(void* const* d_in, const int* in_sizes, int n_in,
                              void* d_out, int out_size, void* d_ws, size_t ws_size,
                              hipStream_t stream) {
    const int n = in_sizes[0] / 18;           // batch count (1048576)
    const int grid = (n + BLOCK - 1) / BLOCK;
    lstm_fused<<<grid, BLOCK, 0, stream>>>(
        (const float*)d_in[0],
        (const float*)d_in[1], (const float*)d_in[2],
        (const float*)d_in[3], (const float*)d_in[4],
        (const float*)d_in[5], (const float*)d_in[6],
        (const float*)d_in[7], (const float*)d_in[8],
        (const float*)d_in[9], (const float*)d_in[10],
        (const float*)d_in[11], (const float*)d_in[12],
        (const float*)d_in[13], (const float*)d_in[14],
        (const float*)d_in[15], (const float*)d_in[16],
        (float*)d_out, n);
}

// Round 3
// 3503.037 us; speedup vs baseline: 6.7108x; 6.7108x over previous
//
#include <hip/hip_runtime.h>

#define BLOCK 256
#define HROW 72   // LDS h-tile row stride in halves (144 B): breaks pow2 bank pattern

typedef _Float16 half_t;
typedef __attribute__((ext_vector_type(8))) _Float16 half8;
typedef __attribute__((ext_vector_type(4))) float float4v;

__device__ __forceinline__ float sigm(float x) {
    return __fdividef(1.0f, 1.0f + __expf(-x));
}
__device__ __forceinline__ float tanhfast(float x) {
    return 1.0f - 2.0f * __fdividef(1.0f, 1.0f + __expf(2.0f * x));
}

// ---------------- MLP kernel: per-thread b, full-width utilization ----------------
// Writes out[b] = pb + hid2 @ pW[:,256:288].T  (the LSTM kernel accumulates on top)
extern "C" __global__ void __launch_bounds__(BLOCK, 1) mlp_kernel(
    const float* __restrict__ inputs,
    const float* __restrict__ mW0, const float* __restrict__ mb0,
    const float* __restrict__ mW1, const float* __restrict__ mb1,
    const float* __restrict__ mW2, const float* __restrict__ mb2,
    const float* __restrict__ pW, const float* __restrict__ pb,
    float* __restrict__ out, int n)
{
    int b = blockIdx.x * BLOCK + threadIdx.x;
    if (b >= n) return;
    float f0 = inputs[(size_t)b * 18 + 16], f1 = inputs[(size_t)b * 18 + 17];
    float h0[64];
    #pragma unroll
    for (int i = 0; i < 64; ++i)
        h0[i] = fmaxf(mW0[2 * i] * f0 + mW0[2 * i + 1] * f1 + mb0[i], 0.0f);
    float h1[64];
    #pragma unroll 2
    for (int i = 0; i < 64; ++i) {
        float a = mb1[i];
        #pragma unroll
        for (int k = 0; k < 64; ++k) a += mW1[i * 64 + k] * h0[k];
        h1[i] = fmaxf(a, 0.0f);
    }
    float out0 = pb[0], out1 = pb[1];
    #pragma unroll 2
    for (int i = 0; i < 32; ++i) {
        float a = mb2[i];
        #pragma unroll
        for (int k = 0; k < 64; ++k) a += mW2[i * 64 + k] * h1[k];
        out0 += pW[256 + i] * a;
        out1 += pW[288 + 256 + i] * a;
    }
    ((float2*)out)[b] = make_float2(out0, out1);
}

// ---------------- LSTM MFMA kernel ----------------
// Workgroup = 64 batch rows, 4 waves. Wave w owns j-columns [16w,16w+16) and
// gate tiles n = j + {0,64,128,192}, all 4 batch subtiles (mt).
// Layouts (gfx950 16x16x32, m89/m120-verified):
//   C/D: col(n) = lane&15, row(m) = (lane>>4)*4 + reg
//   A  : A[m = lane&15][k = (lane>>4)*8 + i]  (i in 0..7)
//   B  : B[k = (lane>>4)*8 + i][n = lane&15]
__device__ __forceinline__ void lstm_mfma_one(
    const float* __restrict__ Wih, const float* __restrict__ Whh,
    const float* __restrict__ bih, const float* __restrict__ bhh,
    const float* __restrict__ pW, int zbase,        // z col base: h at zbase, c at zbase+64
    const float* __restrict__ xt,                   // xt[t*64 + b] for this LSTM (t in 0..7)
    half_t* __restrict__ hbuf,                      // [2][64*HROW]
    int w, int lane,
    float po0[4][4], float po1[4][4])
{
    const int l15  = lane & 15;
    const int quad = lane >> 4;
    const int jcol = w * 16 + l15;

    // --- one-time weight fragments (registers, reused 7 steps) ---
    half8 Bf[4][2];
    float wih_v[4], bias_v[4];
    #pragma unroll
    for (int gg = 0; gg < 4; ++gg) {
        const int nrow = gg * 64 + jcol;
        #pragma unroll
        for (int kf = 0; kf < 2; ++kf) {
            const float4* p = (const float4*)(Whh + nrow * 64 + kf * 32 + quad * 8);
            float4 w0 = p[0], w1 = p[1];
            Bf[gg][kf] = half8{(half_t)w0.x, (half_t)w0.y, (half_t)w0.z, (half_t)w0.w,
                               (half_t)w1.x, (half_t)w1.y, (half_t)w1.z, (half_t)w1.w};
        }
        wih_v[gg]  = Wih[nrow];
        bias_v[gg] = bih[nrow] + bhh[nrow];
    }

    float4v cst[4];

    // --- t = 0: h = c = 0 -> gates = x0*Wih + b (no MFMA) ---
    #pragma unroll
    for (int mt = 0; mt < 4; ++mt) {
        float4v x4 = *(const float4v*)&xt[0 * 64 + mt * 16 + quad * 4];
        #pragma unroll
        for (int reg = 0; reg < 4; ++reg) {
            float gi = x4[reg] * wih_v[0] + bias_v[0];
            float gG = x4[reg] * wih_v[2] + bias_v[2];
            float gO = x4[reg] * wih_v[3] + bias_v[3];
            float cn = sigm(gi) * tanhfast(gG);
            cst[mt][reg] = cn;
            float hv = sigm(gO) * tanhfast(cn);
            hbuf[(mt * 16 + quad * 4 + reg) * HROW + jcol] = (half_t)hv;  // buf 0
        }
    }
    __syncthreads();

    // --- t = 1..7 ---
    #pragma unroll 1
    for (int t = 1; t < 8; ++t) {
        const half_t* hsrc = hbuf + ((t + 1) & 1) * (64 * HROW);  // parity of t-1
        half_t*       hdst = hbuf + (t & 1) * (64 * HROW);
        float4v acc[4][4];
        #pragma unroll
        for (int mt = 0; mt < 4; ++mt) {
            float4v x4 = *(const float4v*)&xt[t * 64 + mt * 16 + quad * 4];
            half8 a0 = *(const half8*)&hsrc[(mt * 16 + l15) * HROW + quad * 8];
            half8 a1 = *(const half8*)&hsrc[(mt * 16 + l15) * HROW + 32 + quad * 8];
            #pragma unroll
            for (int gg = 0; gg < 4; ++gg) {
                float4v ai;
                #pragma unroll
                for (int reg = 0; reg < 4; ++reg) ai[reg] = x4[reg] * wih_v[gg] + bias_v[gg];
                ai = __builtin_amdgcn_mfma_f32_16x16x32_f16(a0, Bf[gg][0], ai, 0, 0, 0);
                ai = __builtin_amdgcn_mfma_f32_16x16x32_f16(a1, Bf[gg][1], ai, 0, 0, 0);
                acc[mt][gg] = ai;
            }
        }
        #pragma unroll
        for (int mt = 0; mt < 4; ++mt) {
            #pragma unroll
            for (int reg = 0; reg < 4; ++reg) {
                float cn = sigm(acc[mt][1][reg]) * cst[mt][reg]
                         + sigm(acc[mt][0][reg]) * tanhfast(acc[mt][2][reg]);
                cst[mt][reg] = cn;
                float hv = sigm(acc[mt][3][reg]) * tanhfast(cn);
                if (t < 7) {
                    hdst[(mt * 16 + quad * 4 + reg) * HROW + jcol] = (half_t)hv;
                } else {
                    po0[mt][reg] += pW[zbase + jcol] * hv       + pW[zbase + 64 + jcol] * cn;
                    po1[mt][reg] += pW[288 + zbase + jcol] * hv + pW[288 + zbase + 64 + jcol] * cn;
                }
            }
        }
        __syncthreads();   // also protects buffer reuse across LSTM1 -> LSTM2
    }
}

extern "C" __global__ void __launch_bounds__(BLOCK, 1) lstm_mfma(
    const float* __restrict__ inputs,
    const float* __restrict__ Wih1, const float* __restrict__ Whh1,
    const float* __restrict__ bih1, const float* __restrict__ bhh1,
    const float* __restrict__ Wih2, const float* __restrict__ Whh2,
    const float* __restrict__ bih2, const float* __restrict__ bhh2,
    const float* __restrict__ pW,
    float* __restrict__ out, int n)
{
    __shared__ half_t hbuf[2 * 64 * HROW];   // 18.0 KB, double-buffered h tile
    __shared__ float  xt_lds[16 * 64];       // 4 KB: x transposed [t][b]
    __shared__ float  wp[4][64][2];          // 2 KB: per-wave projection partials

    const int tid  = threadIdx.x;
    const int w    = tid >> 6;
    const int lane = tid & 63;
    const int base = blockIdx.x * 64;

    // stage x[b][0..15] transposed -> xt_lds[t*64+b]; global reads coalesced
    for (int idx = tid; idx < 64 * 18; idx += BLOCK) {
        int row = idx / 18, c = idx % 18;
        float v = inputs[(size_t)(base + row) * 18 + c];
        if (c < 16) xt_lds[c * 64 + row] = v;
    }
    __syncthreads();

    float po0[4][4], po1[4][4];
    #pragma unroll
    for (int mt = 0; mt < 4; ++mt)
        #pragma unroll
        for (int reg = 0; reg < 4; ++reg) { po0[mt][reg] = 0.0f; po1[mt][reg] = 0.0f; }

    lstm_mfma_one(Wih1, Whh1, bih1, bhh1, pW, 0,   xt_lds,           hbuf, w, lane, po0, po1);
    lstm_mfma_one(Wih2, Whh2, bih2, bhh2, pW, 128, xt_lds + 8 * 64,  hbuf, w, lane, po0, po1);

    // butterfly-reduce over the 16 lanes sharing each batch row (j dimension)
    #pragma unroll
    for (int mt = 0; mt < 4; ++mt)
        #pragma unroll
        for (int reg = 0; reg < 4; ++reg) {
            float a = po0[mt][reg], b2 = po1[mt][reg];
            #pragma unroll
            for (int s = 1; s < 16; s <<= 1) {
                a  += __shfl_xor(a,  s, 64);
                b2 += __shfl_xor(b2, s, 64);
            }
            po0[mt][reg] = a; po1[mt][reg] = b2;
        }
    if ((lane & 15) == 0) {
        const int quad = lane >> 4;
        #pragma unroll
        for (int mt = 0; mt < 4; ++mt)
            #pragma unroll
            for (int reg = 0; reg < 4; ++reg) {
                int b = mt * 16 + quad * 4 + reg;
                wp[w][b][0] = po0[mt][reg];
                wp[w][b][1] = po1[mt][reg];
            }
    }
    __syncthreads();
    if (tid < 64) {
        int gb = base + tid;
        float2 o = ((float2*)out)[gb];   // MLP kernel ran first on this stream
        o.x += wp[0][tid][0] + wp[1][tid][0] + wp[2][tid][0] + wp[3][tid][0];
        o.y += wp[0][tid][1] + wp[1][tid][1] + wp[2][tid][1] + wp[3][tid][1];
        ((float2*)out)[gb] = o;
    }
}

extern "C" void kernel_launch(void* const* d_in, const int* in_sizes, int n_in,
                              void* d_out, int out_size, void* d_ws, size_t ws_size,
                              hipStream_t stream) {
    const int n = in_sizes[0] / 18;           // 1048576
    mlp_kernel<<<(n + BLOCK - 1) / BLOCK, BLOCK, 0, stream>>>(
        (const float*)d_in[0],
        (const float*)d_in[9],  (const float*)d_in[10],
        (const float*)d_in[11], (const float*)d_in[12],
        (const float*)d_in[13], (const float*)d_in[14],
        (const float*)d_in[15], (const float*)d_in[16],
        (float*)d_out, n);
    lstm_mfma<<<n / 64, BLOCK, 0, stream>>>(
        (const float*)d_in[0],
        (const float*)d_in[1], (const float*)d_in[2],
        (const float*)d_in[3], (const float*)d_in[4],
        (const float*)d_in[5], (const float*)d_in[6],
        (const float*)d_in[7], (const float*)d_in[8],
        (const float*)d_in[15],
        (float*)d_out, n);
}

// Round 4
// 2234.341 us; speedup vs baseline: 10.5214x; 1.5678x over previous
//
#include <hip/hip_runtime.h>

#define BLOCK 256
#define HROW 72   // LDS h-tile row stride in halves (144 B)

typedef _Float16 half_t;
typedef __attribute__((ext_vector_type(8))) _Float16 half8;
typedef __attribute__((ext_vector_type(4))) float float4v;

#define L2E  1.4426950408889634f
#define L2E2 2.8853900817779268f

__device__ __forceinline__ float rcp_(float x) { return __builtin_amdgcn_rcpf(x); }
__device__ __forceinline__ float ex2(float x)  { return __builtin_amdgcn_exp2f(x); }

// ---------------- MLP kernel ----------------
// acc2[32] on-the-fly accumulation instead of h1[64]: ~115 live VGPRs -> 4 waves/SIMD.
extern "C" __global__ void __launch_bounds__(BLOCK, 1) mlp_kernel(
    const float* __restrict__ inputs,
    const float* __restrict__ mW0, const float* __restrict__ mb0,
    const float* __restrict__ mW1, const float* __restrict__ mb1,
    const float* __restrict__ mW2, const float* __restrict__ mb2,
    const float* __restrict__ pW, const float* __restrict__ pb,
    float* __restrict__ out, int n)
{
    int b = blockIdx.x * BLOCK + threadIdx.x;
    if (b >= n) return;
    float f0 = inputs[(size_t)b * 18 + 16], f1 = inputs[(size_t)b * 18 + 17];
    float h0[64];
    #pragma unroll
    for (int i = 0; i < 64; ++i)
        h0[i] = fmaxf(fmaf(mW0[2 * i], f0, fmaf(mW0[2 * i + 1], f1, mb0[i])), 0.0f);
    float acc2[32];
    #pragma unroll
    for (int j = 0; j < 32; ++j) acc2[j] = mb2[j];
    #pragma unroll 2
    for (int i = 0; i < 64; ++i) {
        float a = mb1[i];
        #pragma unroll
        for (int k = 0; k < 64; ++k) a = fmaf(mW1[i * 64 + k], h0[k], a);
        a = fmaxf(a, 0.0f);
        #pragma unroll
        for (int j = 0; j < 32; ++j) acc2[j] = fmaf(mW2[j * 64 + i], a, acc2[j]);
    }
    float out0 = pb[0], out1 = pb[1];
    #pragma unroll
    for (int j = 0; j < 32; ++j) {
        out0 = fmaf(pW[256 + j], acc2[j], out0);
        out1 = fmaf(pW[288 + 256 + j], acc2[j], out1);
    }
    ((float2*)out)[b] = make_float2(out0, out1);
}

// ---------------- LSTM step (inlined; LAST folds projection in) ----------------
// Gate preactivations arrive PRE-SCALED by log2e (2*log2e for g) via weight scaling,
// so activations are bare v_exp_f32 + fused-rcp algebra:
//   s(i)*tanh(g) = (Bi*Bg - Bi) / ((1+Bi)(1+Bg)),  s(f) = Bf/(1+Bf)
template <bool LAST>
__device__ __forceinline__ void lstm_step(
    const float* __restrict__ xt,          // xt + t*64
    const half_t* __restrict__ src, half_t* __restrict__ dst,
    const half8 Bf[4][2], const float wih_v[4], const float bias_v[4],
    int l15, int quad, int jcol,
    float4v cst[4],
    float ph0, float pc0, float ph1, float pc1,
    float4v po0[4], float4v po1[4])
{
    float4v acc[4][4];
    #pragma unroll
    for (int mt = 0; mt < 4; ++mt) {
        float4v x4 = *(const float4v*)&xt[mt * 16 + quad * 4];
        half8 a0 = *(const half8*)&src[(mt * 16 + l15) * HROW + quad * 8];
        half8 a1 = *(const half8*)&src[(mt * 16 + l15) * HROW + 32 + quad * 8];
        #pragma unroll
        for (int gg = 0; gg < 4; ++gg) {
            float4v ai;
            #pragma unroll
            for (int reg = 0; reg < 4; ++reg) ai[reg] = fmaf(x4[reg], wih_v[gg], bias_v[gg]);
            ai = __builtin_amdgcn_mfma_f32_16x16x32_f16(a0, Bf[gg][0], ai, 0, 0, 0);
            ai = __builtin_amdgcn_mfma_f32_16x16x32_f16(a1, Bf[gg][1], ai, 0, 0, 0);
            acc[mt][gg] = ai;
        }
    }
    #pragma unroll
    for (int mt = 0; mt < 4; ++mt) {
        #pragma unroll
        for (int reg = 0; reg < 4; ++reg) {
            float Bi  = ex2(acc[mt][0][reg]);
            float Bff = ex2(acc[mt][1][reg]);
            float Bg  = ex2(acc[mt][2][reg]);
            float Bo  = ex2(acc[mt][3][reg]);
            float ig  = fmaf(Bi, Bg, -Bi) * rcp_((1.0f + Bi) * (1.0f + Bg));
            float cn  = fmaf(Bff * rcp_(1.0f + Bff), cst[mt][reg], ig);
            cst[mt][reg] = cn;
            float Cc  = ex2(cn * L2E2);
            float hv  = fmaf(Bo, Cc, -Bo) * rcp_((1.0f + Bo) * (1.0f + Cc));
            if (LAST) {
                po0[mt][reg] = fmaf(ph0, hv, fmaf(pc0, cn, po0[mt][reg]));
                po1[mt][reg] = fmaf(ph1, hv, fmaf(pc1, cn, po1[mt][reg]));
            } else {
                dst[(mt * 16 + quad * 4 + reg) * HROW + jcol] = (half_t)hv;
            }
        }
    }
    __syncthreads();
}

__device__ __forceinline__ void lstm_mfma_one(
    const float* __restrict__ Wih, const float* __restrict__ Whh,
    const float* __restrict__ bih, const float* __restrict__ bhh,
    const float* __restrict__ pW, int zbase,
    const float* __restrict__ xt,            // xt[t*64 + b], t in 0..7
    half_t* __restrict__ hbuf,               // [2][64*HROW]
    int w, int lane,
    float4v po0[4], float4v po1[4])
{
    const int l15  = lane & 15;
    const int quad = lane >> 4;
    const int jcol = w * 16 + l15;

    // --- weight fragments, PRE-SCALED by log2e (g-gate by 2*log2e) ---
    const float gscale[4] = {L2E, L2E, L2E2, L2E};
    half8 Bf[4][2];
    float wih_v[4], bias_v[4];
    #pragma unroll
    for (int gg = 0; gg < 4; ++gg) {
        const int nrow = gg * 64 + jcol;
        const float s = gscale[gg];
        #pragma unroll
        for (int kf = 0; kf < 2; ++kf) {
            const float4* p = (const float4*)(Whh + nrow * 64 + kf * 32 + quad * 8);
            float4 w0 = p[0], w1 = p[1];
            Bf[gg][kf] = half8{(half_t)(w0.x * s), (half_t)(w0.y * s), (half_t)(w0.z * s), (half_t)(w0.w * s),
                               (half_t)(w1.x * s), (half_t)(w1.y * s), (half_t)(w1.z * s), (half_t)(w1.w * s)};
        }
        wih_v[gg]  = Wih[nrow] * s;
        bias_v[gg] = (bih[nrow] + bhh[nrow]) * s;
    }

    float4v cst[4];

    // --- t = 0: h = c = 0 -> preacts = x*wih_s + b_s (already log2e-scaled) ---
    #pragma unroll
    for (int mt = 0; mt < 4; ++mt) {
        float4v x4 = *(const float4v*)&xt[mt * 16 + quad * 4];
        #pragma unroll
        for (int reg = 0; reg < 4; ++reg) {
            float Bi = ex2(fmaf(x4[reg], wih_v[0], bias_v[0]));
            float Bg = ex2(fmaf(x4[reg], wih_v[2], bias_v[2]));
            float Bo = ex2(fmaf(x4[reg], wih_v[3], bias_v[3]));
            float cn = fmaf(Bi, Bg, -Bi) * rcp_((1.0f + Bi) * (1.0f + Bg));
            cst[mt][reg] = cn;
            float Cc = ex2(cn * L2E2);
            float hv = fmaf(Bo, Cc, -Bo) * rcp_((1.0f + Bo) * (1.0f + Cc));
            hbuf[(mt * 16 + quad * 4 + reg) * HROW + jcol] = (half_t)hv;  // buf 0
        }
    }
    __syncthreads();

    const float ph0 = pW[zbase + jcol],       pc0 = pW[zbase + 64 + jcol];
    const float ph1 = pW[288 + zbase + jcol], pc1 = pW[288 + zbase + 64 + jcol];

    half_t* b0 = hbuf;
    half_t* b1 = hbuf + 64 * HROW;
    // steps 1..6 as 3 double-buffered pairs (2 code bodies), step 7 peeled with projection
    #pragma unroll 1
    for (int tt = 1; tt < 7; tt += 2) {
        lstm_step<false>(xt + tt * 64,       b0, b1, Bf, wih_v, bias_v, l15, quad, jcol,
                         cst, ph0, pc0, ph1, pc1, po0, po1);
        lstm_step<false>(xt + (tt + 1) * 64, b1, b0, Bf, wih_v, bias_v, l15, quad, jcol,
                         cst, ph0, pc0, ph1, pc1, po0, po1);
    }
    lstm_step<true>(xt + 7 * 64, b0, b1, Bf, wih_v, bias_v, l15, quad, jcol,
                    cst, ph0, pc0, ph1, pc1, po0, po1);
}

extern "C" __global__ void __launch_bounds__(BLOCK, 1) lstm_mfma(
    const float* __restrict__ inputs,
    const float* __restrict__ Wih1, const float* __restrict__ Whh1,
    const float* __restrict__ bih1, const float* __restrict__ bhh1,
    const float* __restrict__ Wih2, const float* __restrict__ Whh2,
    const float* __restrict__ bih2, const float* __restrict__ bhh2,
    const float* __restrict__ pW,
    float* __restrict__ out, int n)
{
    __shared__ half_t hbuf[2 * 64 * HROW];   // 18 KB double-buffered h tile
    __shared__ float  xt_lds[16 * 64];       // x transposed [t][b]
    __shared__ float  wp[4][64][2];          // per-wave projection partials

    const int tid  = threadIdx.x;
    const int w    = tid >> 6;
    const int lane = tid & 63;
    const int base = blockIdx.x * 64;

    for (int idx = tid; idx < 64 * 18; idx += BLOCK) {
        int row = idx / 18, c = idx % 18;
        float v = inputs[(size_t)(base + row) * 18 + c];
        if (c < 16) xt_lds[c * 64 + row] = v;
    }
    __syncthreads();

    float4v po0[4], po1[4];
    #pragma unroll
    for (int mt = 0; mt < 4; ++mt) { po0[mt] = float4v{0,0,0,0}; po1[mt] = float4v{0,0,0,0}; }

    lstm_mfma_one(Wih1, Whh1, bih1, bhh1, pW, 0,   xt_lds,          hbuf, w, lane, po0, po1);
    lstm_mfma_one(Wih2, Whh2, bih2, bhh2, pW, 128, xt_lds + 8 * 64, hbuf, w, lane, po0, po1);

    // butterfly-reduce over the 16 lanes sharing each batch row
    #pragma unroll
    for (int mt = 0; mt < 4; ++mt)
        #pragma unroll
        for (int reg = 0; reg < 4; ++reg) {
            float a = po0[mt][reg], b2 = po1[mt][reg];
            #pragma unroll
            for (int s = 1; s < 16; s <<= 1) {
                a  += __shfl_xor(a,  s, 64);
                b2 += __shfl_xor(b2, s, 64);
            }
            po0[mt][reg] = a; po1[mt][reg] = b2;
        }
    if ((lane & 15) == 0) {
        const int quad = lane >> 4;
        #pragma unroll
        for (int mt = 0; mt < 4; ++mt)
            #pragma unroll
            for (int reg = 0; reg < 4; ++reg) {
                int b = mt * 16 + quad * 4 + reg;
                wp[w][b][0] = po0[mt][reg];
                wp[w][b][1] = po1[mt][reg];
            }
    }
    __syncthreads();
    if (tid < 64) {
        int gb = base + tid;
        float2 o = ((float2*)out)[gb];   // MLP kernel ran first on this stream
        o.x += wp[0][tid][0] + wp[1][tid][0] + wp[2][tid][0] + wp[3][tid][0];
        o.y += wp[0][tid][1] + wp[1][tid][1] + wp[2][tid][1] + wp[3][tid][1];
        ((float2*)out)[gb] = o;
    }
}

extern "C" void kernel_launch(void* const* d_in, const int* in_sizes, int n_in,
                              void* d_out, int out_size, void* d_ws, size_t ws_size,
                              hipStream_t stream) {
    const int n = in_sizes[0] / 18;           // 1048576
    mlp_kernel<<<(n + BLOCK - 1) / BLOCK, BLOCK, 0, stream>>>(
        (const float*)d_in[0],
        (const float*)d_in[9],  (const float*)d_in[10],
        (const float*)d_in[11], (const float*)d_in[12],
        (const float*)d_in[13], (const float*)d_in[14],
        (const float*)d_in[15], (const float*)d_in[16],
        (float*)d_out, n);
    lstm_mfma<<<n / 64, BLOCK, 0, stream>>>(
        (const float*)d_in[0],
        (const float*)d_in[1], (const float*)d_in[2],
        (const float*)d_in[3], (const float*)d_in[4],
        (const float*)d_in[5], (const float*)d_in[6],
        (const float*)d_in[7], (const float*)d_in[8],
        (const float*)d_in[15],
        (float*)d_out, n);
}

// Round 5
// 1630.127 us; speedup vs baseline: 14.4212x; 1.3707x over previous
//
#include <hip/hip_runtime.h>

#define BLOCK 256
#define HROW 72   // LDS h-tile row stride in halves (144 B): 36 words ≡ 4 mod 32 -> 2-way (free) on b128 reads

typedef _Float16 half_t;
typedef __attribute__((ext_vector_type(8))) _Float16 half8;
typedef __attribute__((ext_vector_type(4))) float float4v;

#define L2E  1.4426950408889634f
#define L2E2 2.8853900817779268f

__device__ __forceinline__ float rcp_(float x) { return __builtin_amdgcn_rcpf(x); }
__device__ __forceinline__ float ex2(float x)  { return __builtin_amdgcn_exp2f(x); }

// ---------------- MLP kernel (near its 157TF vector roofline; untouched) ----------------
extern "C" __global__ void __launch_bounds__(BLOCK, 1) mlp_kernel(
    const float* __restrict__ inputs,
    const float* __restrict__ mW0, const float* __restrict__ mb0,
    const float* __restrict__ mW1, const float* __restrict__ mb1,
    const float* __restrict__ mW2, const float* __restrict__ mb2,
    const float* __restrict__ pW, const float* __restrict__ pb,
    float* __restrict__ out, int n)
{
    int b = blockIdx.x * BLOCK + threadIdx.x;
    if (b >= n) return;
    float f0 = inputs[(size_t)b * 18 + 16], f1 = inputs[(size_t)b * 18 + 17];
    float h0[64];
    #pragma unroll
    for (int i = 0; i < 64; ++i)
        h0[i] = fmaxf(fmaf(mW0[2 * i], f0, fmaf(mW0[2 * i + 1], f1, mb0[i])), 0.0f);
    float acc2[32];
    #pragma unroll
    for (int j = 0; j < 32; ++j) acc2[j] = mb2[j];
    #pragma unroll 2
    for (int i = 0; i < 64; ++i) {
        float a = mb1[i];
        #pragma unroll
        for (int k = 0; k < 64; ++k) a = fmaf(mW1[i * 64 + k], h0[k], a);
        a = fmaxf(a, 0.0f);
        #pragma unroll
        for (int j = 0; j < 32; ++j) acc2[j] = fmaf(mW2[j * 64 + i], a, acc2[j]);
    }
    float out0 = pb[0], out1 = pb[1];
    #pragma unroll
    for (int j = 0; j < 32; ++j) {
        out0 = fmaf(pW[256 + j], acc2[j], out0);
        out1 = fmaf(pW[288 + 256 + j], acc2[j], out1);
    }
    ((float2*)out)[b] = make_float2(out0, out1);
}

// ---------------- LSTM step ----------------
// Per-mt processing: 8 MFMAs + epilogue per batch-subtile -> acc live range is 16
// regs (vs 64 when all 4 subtiles held). LAST folds the projection in and
// butterfly-reduces it into LDS wp immediately -> no persistent po registers.
template <bool LAST>
__device__ __forceinline__ void lstm_step(
    const float* __restrict__ xt,          // xt + t*64
    const half_t* __restrict__ src, half_t* __restrict__ dst,
    const half8 Bf[4][2], const float wih_v[4], const float bias_v[4],
    int l15, int quad, int jcol,
    float4v cst[4],
    const float* __restrict__ pWz,         // pW + zbase (LAST only)
    float* __restrict__ wpw)               // wp[w] base: [64][2] floats (LAST only)
{
    float ph0, pc0, ph1, pc1;
    if (LAST) {
        ph0 = pWz[jcol];       pc0 = pWz[64 + jcol];
        ph1 = pWz[288 + jcol]; pc1 = pWz[288 + 64 + jcol];
    }
    #pragma unroll
    for (int mt = 0; mt < 4; ++mt) {
        float4v x4 = *(const float4v*)&xt[mt * 16 + quad * 4];
        half8 a0 = *(const half8*)&src[(mt * 16 + l15) * HROW + quad * 8];
        half8 a1 = *(const half8*)&src[(mt * 16 + l15) * HROW + 32 + quad * 8];
        float4v ag[4];
        #pragma unroll
        for (int gg = 0; gg < 4; ++gg) {
            float4v ai;
            #pragma unroll
            for (int reg = 0; reg < 4; ++reg) ai[reg] = fmaf(x4[reg], wih_v[gg], bias_v[gg]);
            ai = __builtin_amdgcn_mfma_f32_16x16x32_f16(a0, Bf[gg][0], ai, 0, 0, 0);
            ai = __builtin_amdgcn_mfma_f32_16x16x32_f16(a1, Bf[gg][1], ai, 0, 0, 0);
            ag[gg] = ai;
        }
        float po0[4], po1[4];
        #pragma unroll
        for (int reg = 0; reg < 4; ++reg) {
            float Bi  = ex2(ag[0][reg]);
            float Bff = ex2(ag[1][reg]);
            float Bg  = ex2(ag[2][reg]);
            float Bo  = ex2(ag[3][reg]);
            float ig  = fmaf(Bi, Bg, -Bi) * rcp_((1.0f + Bi) * (1.0f + Bg));
            float cn  = fmaf(Bff * rcp_(1.0f + Bff), cst[mt][reg], ig);
            cst[mt][reg] = cn;
            float Cc  = ex2(cn * L2E2);
            float hv  = fmaf(Bo, Cc, -Bo) * rcp_((1.0f + Bo) * (1.0f + Cc));
            if (LAST) {
                po0[reg] = fmaf(ph0, hv, pc0 * cn);
                po1[reg] = fmaf(ph1, hv, pc1 * cn);
            } else {
                dst[(mt * 16 + quad * 4 + reg) * HROW + jcol] = (half_t)hv;
            }
        }
        if (LAST) {
            // reduce over the 16 j-lanes sharing each batch row, accumulate into wp
            #pragma unroll
            for (int reg = 0; reg < 4; ++reg) {
                #pragma unroll
                for (int s = 1; s < 16; s <<= 1) {
                    po0[reg] += __shfl_xor(po0[reg], s, 64);
                    po1[reg] += __shfl_xor(po1[reg], s, 64);
                }
            }
            if (l15 == 0) {
                #pragma unroll
                for (int reg = 0; reg < 4; ++reg) {
                    int m = mt * 16 + quad * 4 + reg;
                    wpw[m * 2]     += po0[reg];
                    wpw[m * 2 + 1] += po1[reg];
                }
            }
        }
    }
    __syncthreads();
}

__device__ __forceinline__ void lstm_mfma_one(
    const float* __restrict__ Wih, const float* __restrict__ Whh,
    const float* __restrict__ bih, const float* __restrict__ bhh,
    const float* __restrict__ pW, int zbase,
    const float* __restrict__ xt,            // xt[t*64 + b], t in 0..7
    half_t* __restrict__ hbuf,               // [2][64*HROW]
    int w, int lane,
    float* __restrict__ wpw)                 // wp[w] base
{
    const int l15  = lane & 15;
    const int quad = lane >> 4;
    const int jcol = w * 16 + l15;

    // --- weight fragments, PRE-SCALED by log2e (g-gate by 2*log2e) ---
    const float gscale[4] = {L2E, L2E, L2E2, L2E};
    half8 Bf[4][2];
    float wih_v[4], bias_v[4];
    #pragma unroll
    for (int gg = 0; gg < 4; ++gg) {
        const int nrow = gg * 64 + jcol;
        const float s = gscale[gg];
        #pragma unroll
        for (int kf = 0; kf < 2; ++kf) {
            const float4* p = (const float4*)(Whh + nrow * 64 + kf * 32 + quad * 8);
            float4 w0 = p[0], w1 = p[1];
            Bf[gg][kf] = half8{(half_t)(w0.x * s), (half_t)(w0.y * s), (half_t)(w0.z * s), (half_t)(w0.w * s),
                               (half_t)(w1.x * s), (half_t)(w1.y * s), (half_t)(w1.z * s), (half_t)(w1.w * s)};
        }
        wih_v[gg]  = Wih[nrow] * s;
        bias_v[gg] = (bih[nrow] + bhh[nrow]) * s;
    }

    float4v cst[4];

    // --- t = 0: h = c = 0 -> preacts = x*wih_s + b_s (already log2e-scaled) ---
    #pragma unroll
    for (int mt = 0; mt < 4; ++mt) {
        float4v x4 = *(const float4v*)&xt[mt * 16 + quad * 4];
        #pragma unroll
        for (int reg = 0; reg < 4; ++reg) {
            float Bi = ex2(fmaf(x4[reg], wih_v[0], bias_v[0]));
            float Bg = ex2(fmaf(x4[reg], wih_v[2], bias_v[2]));
            float Bo = ex2(fmaf(x4[reg], wih_v[3], bias_v[3]));
            float cn = fmaf(Bi, Bg, -Bi) * rcp_((1.0f + Bi) * (1.0f + Bg));
            cst[mt][reg] = cn;
            float Cc = ex2(cn * L2E2);
            float hv = fmaf(Bo, Cc, -Bo) * rcp_((1.0f + Bo) * (1.0f + Cc));
            hbuf[(mt * 16 + quad * 4 + reg) * HROW + jcol] = (half_t)hv;  // buf 0
        }
    }
    __syncthreads();

    half_t* b0 = hbuf;
    half_t* b1 = hbuf + 64 * HROW;
    // steps 1..6 as 3 double-buffered pairs, step 7 peeled with projection fold
    #pragma unroll 1
    for (int tt = 1; tt < 7; tt += 2) {
        lstm_step<false>(xt + tt * 64,       b0, b1, Bf, wih_v, bias_v, l15, quad, jcol,
                         cst, pW, wpw);
        lstm_step<false>(xt + (tt + 1) * 64, b1, b0, Bf, wih_v, bias_v, l15, quad, jcol,
                         cst, pW, wpw);
    }
    lstm_step<true>(xt + 7 * 64, b0, b1, Bf, wih_v, bias_v, l15, quad, jcol,
                    cst, pW + zbase, wpw);
}

extern "C" __global__ void __launch_bounds__(BLOCK, 2) lstm_mfma(
    const float* __restrict__ inputs,
    const float* __restrict__ Wih1, const float* __restrict__ Whh1,
    const float* __restrict__ bih1, const float* __restrict__ bhh1,
    const float* __restrict__ Wih2, const float* __restrict__ Whh2,
    const float* __restrict__ bih2, const float* __restrict__ bhh2,
    const float* __restrict__ pW,
    float* __restrict__ out, int n)
{
    __shared__ half_t hbuf[2 * 64 * HROW];   // 18 KB double-buffered h tile
    __shared__ float  xt_lds[16 * 64];       // x transposed [t][b]
    __shared__ float  wp[4][64][2];          // per-wave projection partials (accumulated)

    const int tid  = threadIdx.x;
    const int w    = tid >> 6;
    const int lane = tid & 63;
    const int base = blockIdx.x * 64;

    // zero wp (4*64*2 = 512 floats) and stage x transposed
    ((float2*)wp)[tid] = make_float2(0.0f, 0.0f);
    for (int idx = tid; idx < 64 * 18; idx += BLOCK) {
        int row = idx / 18, c = idx % 18;
        float v = inputs[(size_t)(base + row) * 18 + c];
        if (c < 16) xt_lds[c * 64 + row] = v;
    }
    __syncthreads();

    float* wpw = &wp[w][0][0];
    lstm_mfma_one(Wih1, Whh1, bih1, bhh1, pW, 0,   xt_lds,          hbuf, w, lane, wpw);
    lstm_mfma_one(Wih2, Whh2, bih2, bhh2, pW, 128, xt_lds + 8 * 64, hbuf, w, lane, wpw);

    // final barrier already executed inside the last lstm_step
    if (tid < 64) {
        int gb = base + tid;
        float2 o = ((float2*)out)[gb];   // MLP kernel ran first on this stream
        o.x += wp[0][tid][0] + wp[1][tid][0] + wp[2][tid][0] + wp[3][tid][0];
        o.y += wp[0][tid][1] + wp[1][tid][1] + wp[2][tid][1] + wp[3][tid][1];
        ((float2*)out)[gb] = o;
    }
}

extern "C" void kernel_launch(void* const* d_in, const int* in_sizes, int n_in,
                              void* d_out, int out_size, void* d_ws, size_t ws_size,
                              hipStream_t stream) {
    const int n = in_sizes[0] / 18;           // 1048576
    mlp_kernel<<<(n + BLOCK - 1) / BLOCK, BLOCK, 0, stream>>>(
        (const float*)d_in[0],
        (const float*)d_in[9],  (const float*)d_in[10],
        (const float*)d_in[11], (const float*)d_in[12],
        (const float*)d_in[13], (const float*)d_in[14],
        (const float*)d_in[15], (const float*)d_in[16],
        (float*)d_out, n);
    lstm_mfma<<<n / 64, BLOCK, 0, stream>>>(
        (const float*)d_in[0],
        (const float*)d_in[1], (const float*)d_in[2],
        (const float*)d_in[3], (const float*)d_in[4],
        (const float*)d_in[5], (const float*)d_in[6],
        (const float*)d_in[7], (const float*)d_in[8],
        (const float*)d_in[15],
        (float*)d_out, n);
}